// Round 1
// baseline (336.652 us; speedup 1.0000x reference)
//
#include <hip/hip_runtime.h>
#include <math.h>

#define N_RAYS    65536
#define N_SAMPLES 192
#define NERF_EPS  1e-10f

// Output layout (flat float32, reference return order):
//   rgb_map   [N,3]     offset 0            size 196608
//   density   [N,191]   offset 196608       size 12517376
//   acc_map   [N]       offset 12713984     size 65536
//   weights   [N,192]   offset 12779520     size 12582912
//   depth_map [N]       offset 25362432     size 65536

__global__ __launch_bounds__(256) void nerf_render_kernel(
    const float* __restrict__ raw,       // [N,S,4]
    const float* __restrict__ z_vals,    // [N,S]
    const float* __restrict__ rays_d,    // [N,3]
    float* __restrict__ rgb_map,         // [N,3]
    float* __restrict__ density_out,     // [N,S-1]
    float* __restrict__ acc_map,         // [N]
    float* __restrict__ weights_out,     // [N,S]
    float* __restrict__ depth_map)       // [N]
{
    const int wave = threadIdx.x >> 6;
    const int lane = threadIdx.x & 63;
    const int ray  = blockIdx.x * 4 + wave;
    if (ray >= N_RAYS) return;

    // ray direction norm (broadcast loads, same address across lanes)
    const float dx = rays_d[ray * 3 + 0];
    const float dy = rays_d[ray * 3 + 1];
    const float dz = rays_d[ray * 3 + 2];
    const float dnorm = sqrtf(dx * dx + dy * dy + dz * dz);

    const float4* __restrict__ raw4 = (const float4*)raw;
    const size_t rbase = (size_t)ray * N_SAMPLES;

    float prefix = 1.0f;   // product of t over all previous chunks
    float rsum = 0.f, gsum = 0.f, bsum = 0.f, dsum = 0.f, asum = 0.f;

    #pragma unroll
    for (int c = 0; c < 3; ++c) {
        const int s = c * 64 + lane;

        // coalesced: 64 lanes x 16B contiguous
        const float4 rv = raw4[rbase + s];
        const float  z  = z_vals[rbase + s];
        const float  zn = (s + 1 < N_SAMPLES) ? z_vals[rbase + s + 1] : z;

        const float dist  = fabsf(zn - z) * dnorm;
        const float dens  = fmaxf(rv.w, 0.0f);                 // relu(sigma)
        const float alpha = (s < N_SAMPLES - 1)
                              ? (1.0f - __expf(-dens * dist))
                              : 1.0f;                          // last alpha = 1
        const float t = (1.0f + NERF_EPS) - alpha;             // scan operand

        // exclusive product-scan of t over the 64-lane wave:
        // shift up by 1 (identity 1.0 into lane 0), then inclusive scan.
        float ex = __shfl_up(t, 1);
        if (lane == 0) ex = 1.0f;
        #pragma unroll
        for (int off = 1; off < 64; off <<= 1) {
            const float o = __shfl_up(ex, off);
            if (lane >= off) ex *= o;
        }

        const float trans = prefix * ex;        // exclusive transmittance
        const float w     = alpha * trans;

        // carry: total product of this chunk's t = ex[63] * t[63]
        const float ex63 = __shfl(ex, 63);
        const float t63  = __shfl(t, 63);
        prefix *= ex63 * t63;

        // sigmoid rgb
        const float r_ = 1.0f / (1.0f + __expf(-rv.x));
        const float g_ = 1.0f / (1.0f + __expf(-rv.y));
        const float b_ = 1.0f / (1.0f + __expf(-rv.z));

        rsum += w * r_;
        gsum += w * g_;
        bsum += w * b_;
        dsum += w * z;
        asum += w;

        // coalesced stores
        weights_out[rbase + s] = w;
        if (s < N_SAMPLES - 1)
            density_out[(size_t)ray * (N_SAMPLES - 1) + s] = dens;
    }

    // wave tree-reduction (width 64)
    #pragma unroll
    for (int off = 32; off > 0; off >>= 1) {
        rsum += __shfl_down(rsum, off);
        gsum += __shfl_down(gsum, off);
        bsum += __shfl_down(bsum, off);
        dsum += __shfl_down(dsum, off);
        asum += __shfl_down(asum, off);
    }

    if (lane == 0) {
        rgb_map[ray * 3 + 0] = rsum;
        rgb_map[ray * 3 + 1] = gsum;
        rgb_map[ray * 3 + 2] = bsum;
        depth_map[ray] = dsum;
        acc_map[ray]   = asum;
    }
}

extern "C" void kernel_launch(void* const* d_in, const int* in_sizes, int n_in,
                              void* d_out, int out_size, void* d_ws, size_t ws_size,
                              hipStream_t stream) {
    const float* raw    = (const float*)d_in[0];
    const float* z_vals = (const float*)d_in[1];
    const float* rays_d = (const float*)d_in[2];

    float* out = (float*)d_out;
    float* rgb_map     = out;                       // 65536*3
    float* density_out = out + 196608;              // 65536*191
    float* acc_map     = out + 12713984;            // 65536
    float* weights_out = out + 12779520;            // 65536*192
    float* depth_map   = out + 25362432;            // 65536

    const int blocks = N_RAYS / 4;                  // 4 waves (rays) per block
    nerf_render_kernel<<<blocks, 256, 0, stream>>>(
        raw, z_vals, rays_d,
        rgb_map, density_out, acc_map, weights_out, depth_map);
}

// Round 3
// 322.764 us; speedup vs baseline: 1.0430x; 1.0430x over previous
//
#include <hip/hip_runtime.h>
#include <math.h>

#define N_RAYS    65536
#define N_SAMPLES 192
#define NERF_EPS  1e-10f

// Output layout (flat float32, reference return order):
//   rgb_map   [N,3]     offset 0            size 196608
//   density   [N,191]   offset 196608       size 12517376
//   acc_map   [N]       offset 12713984     size 65536
//   weights   [N,192]   offset 12779520     size 12582912
//   depth_map [N]       offset 25362432     size 65536

typedef float floatx4 __attribute__((ext_vector_type(4)));  // native vector: nontemporal-builtin compatible

__device__ __forceinline__ float fast_sigmoid(float x) {
    // 1/(1+exp(-x)) with HW rcp (~1 ulp) — threshold is 0.104, plenty of margin
    return __builtin_amdgcn_rcpf(1.0f + __expf(-x));
}

__global__ __launch_bounds__(256) void nerf_render_kernel(
    const float* __restrict__ raw,       // [N,S,4]
    const float* __restrict__ z_vals,    // [N,S]
    const float* __restrict__ rays_d,    // [N,3]
    float* __restrict__ rgb_map,         // [N,3]
    float* __restrict__ density_out,     // [N,S-1]
    float* __restrict__ acc_map,         // [N]
    float* __restrict__ weights_out,     // [N,S]
    float* __restrict__ depth_map)       // [N]
{
    const int wave = threadIdx.x >> 6;
    const int lane = threadIdx.x & 63;
    const int ray  = blockIdx.x * 4 + wave;

    // ray direction norm (broadcast loads)
    const float dx = rays_d[ray * 3 + 0];
    const float dy = rays_d[ray * 3 + 1];
    const float dz = rays_d[ray * 3 + 2];
    const float dnorm = sqrtf(dx * dx + dy * dy + dz * dz);

    const floatx4* __restrict__ raw4 = (const floatx4*)raw;
    const size_t rbase = (size_t)ray * N_SAMPLES;

    // ---- issue ALL global loads upfront (memory-level parallelism) ----
    const floatx4 rv0 = __builtin_nontemporal_load(&raw4[rbase + lane]);
    const floatx4 rv1 = __builtin_nontemporal_load(&raw4[rbase + 64 + lane]);
    const floatx4 rv2 = __builtin_nontemporal_load(&raw4[rbase + 128 + lane]);

    const float z0  = z_vals[rbase + lane];
    const float zn0 = z_vals[rbase + lane + 1];
    const float z1  = z_vals[rbase + 64 + lane];
    const float zn1 = z_vals[rbase + 65 + lane];
    const float z2  = z_vals[rbase + 128 + lane];
    // s=191 (lane 63): zn unused (alpha forced to 1) — clamp index
    const float zn2 = z_vals[rbase + ((lane < 63) ? (129 + lane) : 191)];

    // ---- alpha / scan operand t per chunk ----
    const float dens0 = fmaxf(rv0.w, 0.0f);
    const float dens1 = fmaxf(rv1.w, 0.0f);
    const float dens2 = fmaxf(rv2.w, 0.0f);

    const float dist0 = fabsf(zn0 - z0) * dnorm;
    const float dist1 = fabsf(zn1 - z1) * dnorm;
    const float dist2 = fabsf(zn2 - z2) * dnorm;

    const float alpha0 = 1.0f - __expf(-dens0 * dist0);
    const float alpha1 = 1.0f - __expf(-dens1 * dist1);
    const float alpha2 = (lane < 63) ? (1.0f - __expf(-dens2 * dist2)) : 1.0f;

    float t0 = (1.0f + NERF_EPS) - alpha0;
    float t1 = (1.0f + NERF_EPS) - alpha1;
    float t2 = (1.0f + NERF_EPS) - alpha2;

    // ---- three INDEPENDENT exclusive product-scans, interleaved ----
    float e0 = __shfl_up(t0, 1); if (lane == 0) e0 = 1.0f;
    float e1 = __shfl_up(t1, 1); if (lane == 0) e1 = 1.0f;
    float e2 = __shfl_up(t2, 1); if (lane == 0) e2 = 1.0f;
    #pragma unroll
    for (int off = 1; off < 64; off <<= 1) {
        const float a0 = __shfl_up(e0, off);
        const float a1 = __shfl_up(e1, off);
        const float a2 = __shfl_up(e2, off);
        if (lane >= off) { e0 *= a0; e1 *= a1; e2 *= a2; }
    }

    // chunk total products (inclusive value at lane 63)
    const float P0 = __shfl(e0 * t0, 63);
    const float P1 = __shfl(e1 * t1, 63);

    const float trans0 = e0;
    const float trans1 = P0 * e1;
    const float trans2 = (P0 * P1) * e2;

    const float w0 = alpha0 * trans0;
    const float w1 = alpha1 * trans1;
    const float w2 = alpha2 * trans2;

    // ---- sigmoid rgb + per-lane partial sums ----
    const float r0 = fast_sigmoid(rv0.x), g0 = fast_sigmoid(rv0.y), b0 = fast_sigmoid(rv0.z);
    const float r1 = fast_sigmoid(rv1.x), g1 = fast_sigmoid(rv1.y), b1 = fast_sigmoid(rv1.z);
    const float r2 = fast_sigmoid(rv2.x), g2 = fast_sigmoid(rv2.y), b2 = fast_sigmoid(rv2.z);

    float rsum = w0 * r0 + w1 * r1 + w2 * r2;
    float gsum = w0 * g0 + w1 * g1 + w2 * g2;
    float bsum = w0 * b0 + w1 * b1 + w2 * b2;
    float dsum = w0 * z0 + w1 * z1 + w2 * z2;
    float asum = w0 + w1 + w2;

    // ---- streaming stores (no reuse — nontemporal) ----
    __builtin_nontemporal_store(w0, &weights_out[rbase + lane]);
    __builtin_nontemporal_store(w1, &weights_out[rbase + 64 + lane]);
    __builtin_nontemporal_store(w2, &weights_out[rbase + 128 + lane]);

    const size_t dbase = (size_t)ray * (N_SAMPLES - 1);
    __builtin_nontemporal_store(dens0, &density_out[dbase + lane]);
    __builtin_nontemporal_store(dens1, &density_out[dbase + 64 + lane]);
    if (lane < 63)
        __builtin_nontemporal_store(dens2, &density_out[dbase + 128 + lane]);

    // ---- wave tree-reduction (width 64) ----
    #pragma unroll
    for (int off = 32; off > 0; off >>= 1) {
        rsum += __shfl_down(rsum, off);
        gsum += __shfl_down(gsum, off);
        bsum += __shfl_down(bsum, off);
        dsum += __shfl_down(dsum, off);
        asum += __shfl_down(asum, off);
    }

    if (lane == 0) {
        rgb_map[ray * 3 + 0] = rsum;
        rgb_map[ray * 3 + 1] = gsum;
        rgb_map[ray * 3 + 2] = bsum;
        depth_map[ray] = dsum;
        acc_map[ray]   = asum;
    }
}

extern "C" void kernel_launch(void* const* d_in, const int* in_sizes, int n_in,
                              void* d_out, int out_size, void* d_ws, size_t ws_size,
                              hipStream_t stream) {
    const float* raw    = (const float*)d_in[0];
    const float* z_vals = (const float*)d_in[1];
    const float* rays_d = (const float*)d_in[2];

    float* out = (float*)d_out;
    float* rgb_map     = out;                       // 65536*3
    float* density_out = out + 196608;              // 65536*191
    float* acc_map     = out + 12713984;            // 65536
    float* weights_out = out + 12779520;            // 65536*192
    float* depth_map   = out + 25362432;            // 65536

    const int blocks = N_RAYS / 4;                  // 4 waves (rays) per block
    nerf_render_kernel<<<blocks, 256, 0, stream>>>(
        raw, z_vals, rays_d,
        rgb_map, density_out, acc_map, weights_out, depth_map);
}